// Round 2
// baseline (78.320 us; speedup 1.0000x reference)
//
#include <hip/hip_runtime.h>
#include <stdint.h>
#include <math.h>

#define NBOX 18
#define BB 512
#define DD 2048
#define NOBJ 16
#define KK 3
#define NCLS 174
#define NCAT 321
#define NCAND (BB * NOBJ) /* 8192 */

// ---------------- threefry2x32 (JAX-exact, 20 rounds) ----------------
__host__ __device__ __forceinline__ uint32_t rotl32(uint32_t x, int d) {
  return (x << d) | (x >> (32 - d));
}

__host__ __device__ __forceinline__ void threefry2x32(uint32_t k0, uint32_t k1,
                                                      uint32_t x0, uint32_t x1,
                                                      uint32_t& o0, uint32_t& o1) {
  uint32_t ks2 = k0 ^ k1 ^ 0x1BD11BDAu;
  x0 += k0; x1 += k1;
#define TFR(r) x0 += x1; x1 = rotl32(x1, r); x1 ^= x0;
#define R4A TFR(13) TFR(15) TFR(26) TFR(6)
#define R4B TFR(17) TFR(29) TFR(16) TFR(24)
  R4A x0 += k1;  x1 += ks2 + 1u;
  R4B x0 += ks2; x1 += k0 + 2u;
  R4A x0 += k0;  x1 += k1 + 3u;
  R4B x0 += k1;  x1 += ks2 + 4u;
  R4A x0 += ks2; x1 += k0 + 5u;
#undef R4A
#undef R4B
#undef TFR
  o0 = x0; o1 = x1;
}

__device__ __forceinline__ float bits_to_unit(uint32_t bits) {
  // XLA uniform bit trick: mantissa from top 23 bits -> [1,2) - 1
  float f = __uint_as_float((bits >> 9) | 0x3f800000u);
  return f - 1.0f;
}

// ---------------- kernel 0: log co-occurrence table ----------------
__global__ void logcooc_kernel(const float* __restrict__ cooc, float* __restrict__ lc) {
  int i = blockIdx.x * 256 + threadIdx.x;
  if (i < NCLS * NCAT) {
    float c = cooc[i];
    lc[i] = (c > 0.0f) ? logf(c) : -INFINITY;
  }
}

// ---------------- kernel 1: ori_comp = mean over 18 boxes ----------------
__global__ void ori_kernel(const float* __restrict__ obj_fea, float* __restrict__ ori) {
  int b = blockIdx.x;
  int tid = threadIdx.x;
  const float4* src = (const float4*)(obj_fea + (size_t)b * NBOX * DD);
  float4* dst = (float4*)(ori + (size_t)b * DD);
  for (int c = tid; c < DD / 4; c += 256) {
    float4 acc = make_float4(0.f, 0.f, 0.f, 0.f);
    for (int r = 0; r < NBOX; r++) {
      float4 v = src[r * (DD / 4) + c];
      acc.x += v.x; acc.y += v.y; acc.z += v.z; acc.w += v.w;
    }
    const float s = 1.0f / 18.0f;
    acc.x *= s; acc.y *= s; acc.z *= s; acc.w *= s;
    dst[c] = acc;
  }
}

// ---------------- kernel 2: Gumbel-argmax sampling + lam + slots + has_cand ----------------
__global__ void sample_kernel(const float* __restrict__ logcooc,
                              const int* __restrict__ obj_cat,
                              const int* __restrict__ obj_ind,
                              const int* __restrict__ labels,
                              uint32_t r1h, uint32_t r1l,
                              uint32_t r2h, uint32_t r2l,
                              uint32_t r3bh, uint32_t r3bl,
                              int* __restrict__ sel, int* __restrict__ slots,
                              float* __restrict__ lam, int* __restrict__ hasc) {
  int b = blockIdx.x;
  int k = blockIdx.y;
  int tid = threadIdx.x;
  int lab = labels[b];
  const float* lrow = logcooc + lab * NCAT;

  float best = -INFINITY;
  int bidx = 0;
  uint32_t base = ((uint32_t)(k * BB + b)) << 13;  // flat (k,b,j) counter, j in [0,8192)

  for (int j = tid; j < NCAND; j += 256) {
    int jb = j >> 4;
    if (jb == b) continue;  // diagonal masked -> logit = -inf
    int cat = obj_cat[jb * NBOX + 2 + (j & 15)];
    float lw = lrow[cat];
    if (lw == -INFINITY) continue;  // zero co-occurrence -> -inf, can never win
    uint32_t a0, a1;
    threefry2x32(r1h, r1l, 0u, base + (uint32_t)j, a0, a1);
    float u = bits_to_unit(a0 ^ a1);
    if (u == 0.0f) u = 1.1754943508222875e-38f;  // max(tiny, u + tiny)
    float g = -logf(-logf(u));
    float s = g + lw;
    if (s > best) { best = s; bidx = j; }  // strict > keeps first occurrence
  }

  __shared__ float sv[256];
  __shared__ int si[256];
  sv[tid] = best; si[tid] = bidx;
  __syncthreads();
  for (int st = 128; st > 0; st >>= 1) {
    if (tid < st) {
      float v2 = sv[tid + st]; int i2 = si[tid + st];
      if (v2 > sv[tid] || (v2 == sv[tid] && i2 < si[tid])) { sv[tid] = v2; si[tid] = i2; }
    }
    __syncthreads();
  }

  if (tid == 0) {
    int bk = b * KK + k;
    sel[bk] = si[0];
    // slots: randint(r3,(512,3),0,16). JAX randint splits its key:
    // k1,k2 = split(r3); slots = lower_bits % 16, lower_bits = random_bits(k2, (512,3)).
    // r3b (= threefry(r3,(0,1))) is passed in; counter = flat index bk.
    uint32_t s0, s1;
    threefry2x32(r3bh, r3bl, 0u, (uint32_t)bk, s0, s1);
    slots[bk] = (int)((s0 ^ s1) & 15u);
    if (k == 0) {
      int any = 0;
      for (int o = 0; o < NOBJ; o++) any |= (obj_ind[b * NBOX + 2 + o] != 0);
      hasc[b] = (sv[0] != -INFINITY) && any;
      uint32_t c0, c1;
      threefry2x32(r2h, r2l, 0u, (uint32_t)b, c0, c1);
      lam[b] = bits_to_unit(c0 ^ c1);
    }
  }
}

// ---------------- kernel 3: mix_fea ----------------
__global__ void mixfea_kernel(const float* __restrict__ obj_fea,
                              const int* __restrict__ sel, const int* __restrict__ slots,
                              const float* __restrict__ lam, const int* __restrict__ hasc,
                              float* __restrict__ out) {
  int bk = blockIdx.x;
  int b = bk / KK;
  int tid = threadIdx.x;
  float4* o = (float4*)(out + (size_t)bk * DD);
  if (hasc[b]) {
    float l = lam[b];
    float l1 = 1.0f - l;
    int s = sel[bk];
    int bi = s >> 4, bo = s & 15;
    int sl = slots[bk];
    const float4* own = (const float4*)(obj_fea + ((size_t)(b * NBOX + 2 + sl)) * DD);
    const float4* sf  = (const float4*)(obj_fea + ((size_t)(bi * NBOX + 2 + bo)) * DD);
    for (int c = tid; c < DD / 4; c += 256) {
      float4 a = own[c], e = sf[c];
      float4 r;
      r.x = a.x * l + e.x * l1;
      r.y = a.y * l + e.y * l1;
      r.z = a.z * l + e.z * l1;
      r.w = a.w * l + e.w * l1;
      o[c] = r;
    }
  } else {
    const float4* src = (const float4*)(obj_fea + ((size_t)(b * NBOX + 2)) * DD);
    for (int c = tid; c < DD / 4; c += 256) {
      float4 acc = make_float4(0.f, 0.f, 0.f, 0.f);
      for (int o2 = 0; o2 < NOBJ; o2++) {
        float4 v = src[o2 * (DD / 4) + c];
        acc.x += v.x; acc.y += v.y; acc.z += v.z; acc.w += v.w;
      }
      const float s = 1.0f / 16.0f;
      acc.x *= s; acc.y *= s; acc.z *= s; acc.w *= s;
      o[c] = acc;
    }
  }
}

// ---------------- kernel 4: mix_label ----------------
__global__ void mixlabel_kernel(const int* __restrict__ labels,
                                const int* __restrict__ sel,
                                const float* __restrict__ lam,
                                const int* __restrict__ hasc,
                                float* __restrict__ out) {
  int bk = blockIdx.x;
  int b = bk / KK;
  int c = threadIdx.x;
  if (c >= NCLS) return;
  int lb = labels[b];
  float v;
  if (hasc[b]) {
    float l = lam[b];
    int bi = sel[bk] >> 4;
    int ls = labels[bi];
    v = (c == lb ? l : 0.0f) + (c == ls ? (1.0f - l) : 0.0f);
  } else {
    v = (c == lb) ? 1.0f : 0.0f;
  }
  out[(size_t)bk * NCLS + c] = v;
}

extern "C" void kernel_launch(void* const* d_in, const int* in_sizes, int n_in,
                              void* d_out, int out_size, void* d_ws, size_t ws_size,
                              hipStream_t stream) {
  (void)in_sizes; (void)n_in; (void)out_size; (void)ws_size;
  const float* obj_fea = (const float*)d_in[0];
  const float* cooc    = (const float*)d_in[1];
  const int* obj_ind   = (const int*)d_in[2];
  const int* obj_cat   = (const int*)d_in[3];
  const int* labels    = (const int*)d_in[4];

  float* out  = (float*)d_out;
  float* ori  = out;                              // 512*2048
  float* mixf = out + (size_t)BB * DD;            // 512*3*2048
  float* mixl = mixf + (size_t)BB * KK * DD;      // 512*3*174

  char* ws = (char*)d_ws;
  float* logcooc = (float*)ws;                    // 55854 floats (~224 KB)
  int* sel   = (int*)(ws + 224 * 1024);           // 1536
  int* slots = sel + BB * KK;                     // 1536
  int* hasc  = slots + BB * KK;                   // 512
  float* lam = (float*)(hasc + BB);               // 512

  // JAX: key(42) -> split 3, partitionable (fold-like): r_i = threefry(key,(0,i))
  uint32_t r1h, r1l, r2h, r2l, r3h, r3l;
  threefry2x32(0u, 42u, 0u, 0u, r1h, r1l);
  threefry2x32(0u, 42u, 0u, 1u, r2h, r2l);
  threefry2x32(0u, 42u, 0u, 2u, r3h, r3l);
  // randint(r3,...) internally splits: k1,k2 = split(r3); lower_bits uses k2.
  uint32_t r3ah, r3al, r3bh, r3bl;
  threefry2x32(r3h, r3l, 0u, 0u, r3ah, r3al);  // k1 (higher bits, unused: multiplier==0)
  threefry2x32(r3h, r3l, 0u, 1u, r3bh, r3bl);  // k2 (lower bits)
  (void)r3ah; (void)r3al;

  hipLaunchKernelGGL(logcooc_kernel, dim3((NCLS * NCAT + 255) / 256), dim3(256), 0, stream,
                     cooc, logcooc);
  hipLaunchKernelGGL(ori_kernel, dim3(BB), dim3(256), 0, stream, obj_fea, ori);
  hipLaunchKernelGGL(sample_kernel, dim3(BB, KK), dim3(256), 0, stream,
                     logcooc, obj_cat, obj_ind, labels,
                     r1h, r1l, r2h, r2l, r3bh, r3bl,
                     sel, slots, lam, hasc);
  hipLaunchKernelGGL(mixfea_kernel, dim3(BB * KK), dim3(256), 0, stream,
                     obj_fea, sel, slots, lam, hasc, mixf);
  hipLaunchKernelGGL(mixlabel_kernel, dim3(BB * KK), dim3(192), 0, stream,
                     labels, sel, lam, hasc, mixl);
}

// Round 3
// 47.347 us; speedup vs baseline: 1.6542x; 1.6542x over previous
//
#include <hip/hip_runtime.h>
#include <stdint.h>
#include <math.h>

#define NBOX 18
#define BB 512
#define DD 2048
#define NOBJ 16
#define KK 3
#define NCLS 174
#define NCAT 321
#define NCAND 8192
#define TINYF 1.1754943508222875e-38f

// ---------------- threefry2x32 (JAX-exact, 20 rounds) ----------------
__host__ __device__ __forceinline__ uint32_t rotl32(uint32_t x, int d) {
  return (x << d) | (x >> (32 - d));
}

__host__ __device__ __forceinline__ void threefry2x32(uint32_t k0, uint32_t k1,
                                                      uint32_t x0, uint32_t x1,
                                                      uint32_t& o0, uint32_t& o1) {
  uint32_t ks2 = k0 ^ k1 ^ 0x1BD11BDAu;
  x0 += k0; x1 += k1;
#define TFR(r) x0 += x1; x1 = rotl32(x1, r); x1 ^= x0;
#define R4A TFR(13) TFR(15) TFR(26) TFR(6)
#define R4B TFR(17) TFR(29) TFR(16) TFR(24)
  R4A x0 += k1;  x1 += ks2 + 1u;
  R4B x0 += ks2; x1 += k0 + 2u;
  R4A x0 += k0;  x1 += k1 + 3u;
  R4B x0 += k1;  x1 += ks2 + 4u;
  R4A x0 += ks2; x1 += k0 + 5u;
#undef R4A
#undef R4B
#undef TFR
  o0 = x0; o1 = x1;
}

__device__ __forceinline__ float bits_to_unit(uint32_t bits) {
  float f = __uint_as_float((bits >> 9) | 0x3f800000u);
  return f - 1.0f;
}

// ---------------- fused mega-kernel: one block per batch element b ----------------
__global__ __launch_bounds__(512) void prior_mix_kernel(
    const float* __restrict__ obj_fea, const float* __restrict__ cooc,
    const int* __restrict__ obj_ind, const int* __restrict__ obj_cat,
    const int* __restrict__ labels,
    uint32_t r1h, uint32_t r1l, uint32_t r2h, uint32_t r2l,
    uint32_t r3bh, uint32_t r3bl,
    float* __restrict__ ori, float* __restrict__ mixf, float* __restrict__ mixl) {
  const int b = blockIdx.x;
  const int tid = threadIdx.x;
  const int lane = tid & 63;
  const int wid = tid >> 6;  // 8 waves

  __shared__ unsigned short jl[NCAND];  // 16 KB: compacted candidate j (per-wave segments)
  __shared__ float wl[NCAND];           // 32 KB: compacted w = cooc[label, cat_j]
  __shared__ float pval[KK * 8];
  __shared__ int pidx[KK * 8];
  __shared__ int wtot[8];
  __shared__ int s_sel[KK];
  __shared__ int s_slots[KK];
  __shared__ float s_lam;
  __shared__ int s_hasc;

  // ---- p0: issue the 18 ori-row loads; they stay in flight through p1+p2
  const float4* fea4 = (const float4*)obj_fea;
  float4 v[NBOX];
#pragma unroll
  for (int r = 0; r < NBOX; ++r)
    v[r] = fea4[((size_t)b * NBOX + r) * 512 + tid];
  __builtin_amdgcn_sched_barrier(0);  // pin load issue above the compute phases

  // ---- p1: per-wave ordered compaction of valid candidates (no barriers)
  const int lab = labels[b];
  const float* crow = cooc + (size_t)lab * NCAT;
  const int seg = wid << 10;  // wave's 1024-candidate stripe == its LDS segment base
  int cnt = 0;
#pragma unroll 1
  for (int c = 0; c < 16; ++c) {
    int j = seg + (c << 6) + lane;
    int jb = j >> 4;
    float w = 0.0f;
    if (jb != b) w = crow[obj_cat[jb * NBOX + 2 + (j & 15)]];
    unsigned long long m = __ballot(w > 0.0f);
    if (w > 0.0f) {
      int rank = __popcll(m & ((1ull << lane) - 1ull));
      int pos = seg + cnt + rank;
      jl[pos] = (unsigned short)j;
      wl[pos] = w;
    }
    cnt += __popcll(m);
  }
  if (lane == 0) wtot[wid] = cnt;

  // ---- p2: Gumbel-argmax in ratio space: argmax(g + log w) == argmax(w / -log u)
#pragma unroll 1
  for (int k = 0; k < KK; ++k) {
    uint32_t cbase = ((uint32_t)(k * BB + b)) << 13;
    float br = -1.0f;  // best ratio
    int bj = 0;        // best original j
    for (int p = lane; p < cnt; p += 64) {
      uint32_t j = jl[seg + p];
      float w = wl[seg + p];
      uint32_t a0, a1;
      threefry2x32(r1h, r1l, 0u, cbase + j, a0, a1);
      float u = bits_to_unit(a0 ^ a1);
      if (u == 0.0f) u = TINYF;
      float t = -logf(u);  // Exp(1) noise, > 0
      if (w > br * t) { br = w / t; bj = (int)j; }  // strict >: first-index tie-break
    }
#pragma unroll
    for (int mm = 1; mm < 64; mm <<= 1) {
      float ov = __shfl_xor(br, mm, 64);
      int oj = __shfl_xor(bj, mm, 64);
      if (ov > br || (ov == br && oj < bj)) { br = ov; bj = oj; }
    }
    if (lane == 0) { pval[k * 8 + wid] = br; pidx[k * 8 + wid] = bj; }
  }

  // ---- consume the p0 loads (HBM stream overlapped the VALU work above)
  float4 S = v[0];
#pragma unroll
  for (int r = 1; r < NBOX; ++r) { S.x += v[r].x; S.y += v[r].y; S.z += v[r].z; S.w += v[r].w; }
  float4 S16;  // sum of rows 2..17 for the has_cand==0 fallback
  S16.x = S.x - v[0].x - v[1].x; S16.y = S.y - v[0].y - v[1].y;
  S16.z = S.z - v[0].z - v[1].z; S16.w = S.w - v[0].w - v[1].w;
  {
    const float is = 1.0f / 18.0f;
    float4 o; o.x = S.x * is; o.y = S.y * is; o.z = S.z * is; o.w = S.w * is;
    ((float4*)ori)[(size_t)b * 512 + tid] = o;
  }

  __syncthreads();

  // ---- meta: combine wave partials; lam / slots / has_cand
  if (tid == 0) {
    int total = 0;
#pragma unroll
    for (int w8 = 0; w8 < 8; ++w8) total += wtot[w8];
    int any = 0;
    for (int o = 0; o < NOBJ; ++o) any |= (obj_ind[b * NBOX + 2 + o] != 0);
    s_hasc = (total > 0) && any;
    for (int k = 0; k < KK; ++k) {
      float bv = -2.0f; int bj = 0;
      for (int w8 = 0; w8 < 8; ++w8) {  // ascending wave == ascending j: first-argmax kept
        float vv = pval[k * 8 + w8]; int jj = pidx[k * 8 + w8];
        if (vv > bv || (vv == bv && jj < bj)) { bv = vv; bj = jj; }
      }
      s_sel[k] = bj;
      uint32_t s0, s1;
      threefry2x32(r3bh, r3bl, 0u, (uint32_t)(b * KK + k), s0, s1);
      s_slots[k] = (int)((s0 ^ s1) & 15u);
    }
    uint32_t c0, c1;
    threefry2x32(r2h, r2l, 0u, (uint32_t)b, c0, c1);
    s_lam = bits_to_unit(c0 ^ c1);
  }
  __syncthreads();

  // ---- p3: mix_fea + mix_label (all block-local state)
  const int hc = s_hasc;
  const float l = s_lam, l1 = 1.0f - l;
  float4* mixf4 = (float4*)mixf;
  if (hc) {
#pragma unroll 1
    for (int k = 0; k < KK; ++k) {
      int s = s_sel[k];
      int bi = s >> 4, bo = s & 15, sl = s_slots[k];
      float4 a = fea4[((size_t)b * NBOX + 2 + sl) * 512 + tid];
      float4 e = fea4[((size_t)bi * NBOX + 2 + bo) * 512 + tid];
      float4 o;
      o.x = a.x * l + e.x * l1; o.y = a.y * l + e.y * l1;
      o.z = a.z * l + e.z * l1; o.w = a.w * l + e.w * l1;
      mixf4[((size_t)(b * KK + k)) * 512 + tid] = o;
    }
  } else {
    const float is = 1.0f / 16.0f;
    float4 o; o.x = S16.x * is; o.y = S16.y * is; o.z = S16.z * is; o.w = S16.w * is;
#pragma unroll
    for (int k = 0; k < KK; ++k) mixf4[((size_t)(b * KK + k)) * 512 + tid] = o;
  }
  if (tid < NCLS) {
    int lb = labels[b];
#pragma unroll 1
    for (int k = 0; k < KK; ++k) {
      float val;
      if (hc) {
        int ls = labels[s_sel[k] >> 4];
        val = (tid == lb ? l : 0.0f) + (tid == ls ? l1 : 0.0f);
      } else {
        val = (tid == lb) ? 1.0f : 0.0f;
      }
      mixl[(size_t)(b * KK + k) * NCLS + tid] = val;
    }
  }
}

extern "C" void kernel_launch(void* const* d_in, const int* in_sizes, int n_in,
                              void* d_out, int out_size, void* d_ws, size_t ws_size,
                              hipStream_t stream) {
  (void)in_sizes; (void)n_in; (void)out_size; (void)d_ws; (void)ws_size;
  const float* obj_fea = (const float*)d_in[0];
  const float* cooc    = (const float*)d_in[1];
  const int* obj_ind   = (const int*)d_in[2];
  const int* obj_cat   = (const int*)d_in[3];
  const int* labels    = (const int*)d_in[4];

  float* out  = (float*)d_out;
  float* ori  = out;                              // 512*2048
  float* mixf = out + (size_t)BB * DD;            // 512*3*2048
  float* mixl = mixf + (size_t)BB * KK * DD;      // 512*3*174

  // key(42) -> split 3 (partitionable/fold-like): r_i = threefry(key,(0,i))
  uint32_t r1h, r1l, r2h, r2l, r3h, r3l;
  threefry2x32(0u, 42u, 0u, 0u, r1h, r1l);
  threefry2x32(0u, 42u, 0u, 1u, r2h, r2l);
  threefry2x32(0u, 42u, 0u, 2u, r3h, r3l);
  // randint(r3,...) internally splits: k1,k2 = split(r3); lower_bits uses k2
  uint32_t r3bh, r3bl;
  threefry2x32(r3h, r3l, 0u, 1u, r3bh, r3bl);

  hipLaunchKernelGGL(prior_mix_kernel, dim3(BB), dim3(512), 0, stream,
                     obj_fea, cooc, obj_ind, obj_cat, labels,
                     r1h, r1l, r2h, r2l, r3bh, r3bl,
                     ori, mixf, mixl);
}